// Round 1
// baseline (279.170 us; speedup 1.0000x reference)
//
#include <hip/hip_runtime.h>
#include <math.h>
#include <stdint.h>

#define HDIM 128
#define TM 128  // edges per block in the fused MLP kernel (32 per wave)

typedef short s16x8 __attribute__((ext_vector_type(8)));      // 8 bf16 (4 VGPRs) MFMA A/B frag
typedef float f32x4 __attribute__((ext_vector_type(4)));      // MFMA C/D frag
typedef unsigned short ushort8 __attribute__((ext_vector_type(8)));

// fp32 -> bf16 round-to-nearest-even
__device__ __forceinline__ unsigned short f2bf(float x) {
    unsigned u = __float_as_uint(x);
    u += 0x7FFFu + ((u >> 16) & 1u);
    return (unsigned short)(u >> 16);
}

// Abramowitz-Stegun 7.1.26: |err| <= 1.5e-7 absolute.
__device__ __forceinline__ float erf_fast(float x) {
    float ax = fabsf(x);
    float t = __builtin_amdgcn_rcpf(fmaf(0.3275911f, ax, 1.0f));
    float p =        fmaf(t, 1.061405429f, -1.453152027f);
    p = fmaf(t, p, 1.421413741f);
    p = fmaf(t, p, -0.284496736f);
    p = fmaf(t, p, 0.254829592f);
    float e = __builtin_amdgcn_exp2f(ax * ax * -1.4426950408889634f);
    float r = 1.0f - p * t * e;
    return copysignf(r, x);
}

__device__ __forceinline__ float gelu_exact(float x) {
    return 0.5f * x * (1.0f + erf_fast(x * 0.70710678118654752440f));
}

// full-sum over the 16 lanes of a DPP row (n0 group); all lanes get the total.
// VALU-only (mov_dpp+add), replaces ds_bpermute-lowered __shfl_xor chains.
__device__ __forceinline__ float red16(float x) {
    x += __int_as_float(__builtin_amdgcn_update_dpp(0, __float_as_int(x), 0xB1,  0xF, 0xF, true)); // quad_perm [1,0,3,2]
    x += __int_as_float(__builtin_amdgcn_update_dpp(0, __float_as_int(x), 0x4E,  0xF, 0xF, true)); // quad_perm [2,3,0,1]
    x += __int_as_float(__builtin_amdgcn_update_dpp(0, __float_as_int(x), 0x141, 0xF, 0xF, true)); // row_half_mirror
    x += __int_as_float(__builtin_amdgcn_update_dpp(0, __float_as_int(x), 0x140, 0xF, 0xF, true)); // row_mirror
    return x;
}

// async global->LDS 16B per lane; LDS layout must be linear (wave-uniform base + lane*16)
__device__ __forceinline__ void async_cp16(void* lds_dst, const void* g_src) {
    __builtin_amdgcn_global_load_lds(
        (const __attribute__((address_space(1))) unsigned int*)g_src,
        (__attribute__((address_space(3))) unsigned int*)lds_dst,
        16, 0, 0);
}

// ---------------- stable counting-sort kernels ----------------

__global__ void k_hist(const int* __restrict__ groups, int E, int* __restrict__ counts) {
    __shared__ int c[3];
    int t = threadIdx.x;
    if (t < 3) c[t] = 0;
    __syncthreads();
    int base = blockIdx.x * 1024;
    for (int i = t; i < 1024; i += 256) {
        int e = base + i;
        if (e < E) atomicAdd(&c[groups[e]], 1);
    }
    __syncthreads();
    if (t < 3) counts[blockIdx.x * 3 + t] = c[t];
}

__global__ void k_scan(const int* __restrict__ counts, int nChunks,
                       int* __restrict__ bbase, int* __restrict__ gstart, int E) {
    __shared__ int tot[3];
    int t = threadIdx.x;         // block = 192
    int lane = t & 63;
    int g = t >> 6;              // 0..2
    int carry = 0;
    for (int base = 0; base < nChunks; base += 64) {
        int b = base + lane;
        int v = (b < nChunks) ? counts[b * 3 + g] : 0;
        int sc = v;
        #pragma unroll
        for (int off = 1; off < 64; off <<= 1) {
            int u = __shfl_up(sc, off);
            if (lane >= off) sc += u;
        }
        if (b < nChunks) bbase[b * 3 + g] = carry + sc - v;
        carry += __shfl(sc, 63);
    }
    if (lane == 0) tot[g] = carry;
    __syncthreads();
    if (t == 0) {
        gstart[0] = 0;
        gstart[1] = tot[0];
        gstart[2] = tot[0] + tot[1];
        gstart[3] = E;
    }
}

__global__ void k_scatter(const int* __restrict__ groups, int E,
                          const int* __restrict__ bbase, const int* __restrict__ gstart,
                          int* __restrict__ sorted) {
    int b = blockIdx.x;
    int lane = threadIdx.x;  // block = 64 (one wave)
    int run0 = gstart[0] + bbase[b * 3 + 0];
    int run1 = gstart[1] + bbase[b * 3 + 1];
    int run2 = gstart[2] + bbase[b * 3 + 2];
    unsigned long long lt = (1ull << lane) - 1ull;
    for (int p = 0; p < 16; ++p) {
        int e = b * 1024 + p * 64 + lane;
        int g = (e < E) ? groups[e] : 3;
        unsigned long long m0 = __ballot(g == 0);
        unsigned long long m1 = __ballot(g == 1);
        unsigned long long m2 = __ballot(g == 2);
        int pos = 0;
        if (g == 0) pos = run0 + __popcll(m0 & lt);
        else if (g == 1) pos = run1 + __popcll(m1 & lt);
        else if (g == 2) pos = run2 + __popcll(m2 & lt);
        if (e < E) sorted[pos] = e;
        run0 += __popcll(m0);
        run1 += __popcll(m1);
        run2 += __popcll(m2);
    }
}

// ---------------- prep: emb fp32->bf16; W1 swizzled+transposed; W2 transposed ----------------
// W1S[g][n][gk' * 8 .. +7] where gk' = gk ^ (n & 7), gk = k/8  (bank-swizzle for LDS reads)
// W2T[g][n=64][k=128]
__global__ void k_prep(const float* __restrict__ emb, int embElems, int embBlocks,
                       const float* __restrict__ W1, const float* __restrict__ W2,
                       unsigned short* __restrict__ embB,
                       unsigned short* __restrict__ W1S, unsigned short* __restrict__ W2T) {
    if ((int)blockIdx.x < embBlocks) {
        int i = (blockIdx.x * 256 + threadIdx.x) * 8;
        if (i + 8 <= embElems) {
            float4 a = *(const float4*)(emb + i);
            float4 b = *(const float4*)(emb + i + 4);
            ushort8 o;
            o[0] = f2bf(a.x); o[1] = f2bf(a.y); o[2] = f2bf(a.z); o[3] = f2bf(a.w);
            o[4] = f2bf(b.x); o[5] = f2bf(b.y); o[6] = f2bf(b.z); o[7] = f2bf(b.w);
            *(ushort8*)(embB + i) = o;
        } else {
            for (int j = i; j < embElems; ++j) embB[j] = f2bf(emb[j]);
        }
        return;
    }
    int idx = (blockIdx.x - embBlocks) * 256 + threadIdx.x;
    if (idx < 3 * 32 * 128) {                    // W1S: task = (g, gk, n)
        int g  = idx >> 12;
        int r  = idx & 4095;
        int gk = r >> 7;                         // k-granule 0..31 (k0 = gk*8)
        int n  = r & 127;
        const float* src = W1 + (size_t)g * 256 * 128 + (size_t)(gk * 8) * 128 + n;
        ushort8 o;
        #pragma unroll
        for (int j = 0; j < 8; ++j) o[j] = f2bf(src[j * 128]);
        int gks = gk ^ (n & 7);                  // bank swizzle (preserves bit4 -> k-half)
        *(ushort8*)(W1S + ((size_t)(g * 128 + n)) * 256 + gks * 8) = o;
    } else if (idx < 3 * 32 * 128 + 3 * 16 * 64) {
        int r2 = idx - 3 * 32 * 128;             // W2T[g][n=64][k=128]
        int g  = r2 >> 10;
        int r  = r2 & 1023;
        int kc = r >> 6;
        int n  = r & 63;
        const float* src = W2 + (size_t)g * 128 * 64 + (size_t)(kc * 8) * 64 + n;
        ushort8 o;
        #pragma unroll
        for (int j = 0; j < 8; ++j) o[j] = f2bf(src[j * 64]);
        *(ushort8*)(W2T + ((size_t)(g * 64 + n)) * 128 + kc * 8) = o;
    }
}

// ---------------- fused per-edge MLP (MFMA bf16, split-K LDS-staged W1) ----------------
// Block: 256 thr = 4 waves; TM=128 edges, M=32 per wave (2 m-tiles).
// LDS = 34816 B: W1 staged per k-half [128 rows][128 k] bf16 (32KB); sH [128][136] overlays.
// A-frags: depth-2 register pipeline (3 rotating frag pairs = 24 VGPR, was 64).
// GEMM2 B: global W2T (16KB, L1-resident). Reductions: DPP (VALU), not ds_bpermute.
__global__ __launch_bounds__(256, 3)
void k_mlp(const unsigned short* __restrict__ embB,
           const int* __restrict__ edges,
           const int* __restrict__ sorted,
           const int* __restrict__ gstart,
           const unsigned short* __restrict__ W1S,
           const float* __restrict__ b1,
           const float* __restrict__ lng, const float* __restrict__ lnb,
           const unsigned short* __restrict__ W2T,
           const float* __restrict__ b2,
           const float* __restrict__ W3, const float* __restrict__ b3,
           float* __restrict__ out, int E)
{
    __shared__ unsigned char smem[34816];          // W1 half [0,32768); sH [0,34816) overlays
    unsigned short* W1s = (unsigned short*)smem;   // [128 n][128 k-half] bf16
    unsigned short* sH  = (unsigned short*)smem;   // [128][136] bf16

    const int t    = threadIdx.x;
    const int w    = t >> 6;        // wave 0..3
    const int lane = t & 63;
    const int n0   = lane & 15;     // MFMA 16-index
    const int quad = lane >> 4;     // MFMA k-quad / D row-group

    const int pos0 = blockIdx.x * TM;

    int gs1 = gstart[1], gs2 = gstart[2];
    int plast = (pos0 + TM - 1 < E) ? pos0 + TM - 1 : E - 1;
    int g0 = (pos0  >= gs2) ? 2 : (pos0  >= gs1) ? 1 : 0;
    int g1 = (plast >= gs2) ? 2 : (plast >= gs1) ? 1 : 0;

    // ---- per-lane A row pointers (held across the g-loop) ----
    const unsigned short* urow[2];
    const unsigned short* vrow[2];
    #pragma unroll
    for (int mt = 0; mt < 2; ++mt) {
        int p = pos0 + w * 32 + mt * 16 + n0;
        int pc = p < E ? p : E - 1;
        int e  = sorted[pc];
        urow[mt] = embB + (size_t)edges[2 * e]     * HDIM + quad * 8;
        vrow[mt] = embB + (size_t)edges[2 * e + 1] * HDIM + quad * 8;
    }

// load A-frag pair for k-slice ks (0..3 = u-halves, 4..7 = v-halves)
#define LOADA(dst, ks) do {                                                          \
        dst[0] = *(const s16x8*)(((ks) < 4 ? urow[0] : vrow[0]) + (((ks) & 3) * 32));\
        dst[1] = *(const s16x8*)(((ks) < 4 ? urow[1] : vrow[1]) + (((ks) & 3) * 32));\
    } while (0)

// one k-slice of GEMM1 against the staged half (8 nt, 2 mt = 16 MFMA)
#define KSTEP(areg, ks) do {                                                                  \
        _Pragma("unroll")                                                                     \
        for (int nt = 0; nt < 8; ++nt) {                                                      \
            int gkl = ((((ks) * 4 + quad) ^ (n0 & 7)) & 15);                                  \
            s16x8 bfrag = *(const s16x8*)(&W1s[(nt * 16 + n0) * 128 + gkl * 8]);              \
            acc[0][nt] = __builtin_amdgcn_mfma_f32_16x16x32_bf16(areg[0], bfrag, acc[0][nt], 0, 0, 0); \
            acc[1][nt] = __builtin_amdgcn_mfma_f32_16x16x32_bf16(areg[1], bfrag, acc[1][nt], 0, 0, 0); \
        }                                                                                     \
    } while (0)

    for (int g = g0; g <= g1; ++g) {
        const unsigned char* srcg = (const unsigned char*)(W1S + (size_t)g * 128 * 256);
        const int sn = t >> 4, sj = t & 15;      // staging row-in-granule / 16B column

        // ---- stage k-half 0 (32KB) ----
        #pragma unroll
        for (int r = 0; r < 8; ++r)
            async_cp16(smem + r * 4096 + t * 16, srcg + (size_t)(r * 16 + sn) * 512 + sj * 16);

        f32x4 acc[2][8];
        #pragma unroll
        for (int mt = 0; mt < 2; ++mt)
            #pragma unroll
            for (int nt = 0; nt < 8; ++nt) acc[mt][nt] = (f32x4){0.f, 0.f, 0.f, 0.f};

        s16x8 aA[2], aB[2], aC[2];
        LOADA(aA, 0); LOADA(aB, 1);              // in flight across the barrier

        // hoist epilogue constants (overlap staging)
        float b1v[8], lgv[8], lbv[8];
        #pragma unroll
        for (int nt = 0; nt < 8; ++nt) {
            int c = nt * 16 + n0;
            b1v[nt] = b1[g * HDIM + c];
            lgv[nt] = lng[g * HDIM + c];
            lbv[nt] = lnb[g * HDIM + c];
        }
        float b2v[4], w3v[4];
        #pragma unroll
        for (int nt2 = 0; nt2 < 4; ++nt2) {
            int c = nt2 * 16 + n0;
            b2v[nt2] = b2[g * 64 + c];
            w3v[nt2] = W3[g * 64 + c];
        }
        float bias3 = b3[g];

        __syncthreads();   // (1) half-0 staged; aA/aB arrived

        // ---- GEMM1 k-half 0: ks = 0..3 ----
        LOADA(aC, 2); KSTEP(aA, 0);
        LOADA(aA, 3); KSTEP(aB, 1);
        LOADA(aB, 4); KSTEP(aC, 2);
        LOADA(aC, 5); KSTEP(aA, 3);

        __syncthreads();   // (2) half-0 reads done; buffer reusable

        // ---- stage k-half 1 (32KB) into same buffer ----
        #pragma unroll
        for (int r = 0; r < 8; ++r)
            async_cp16(smem + r * 4096 + t * 16, srcg + (size_t)(r * 16 + sn) * 512 + 256 + sj * 16);

        __syncthreads();   // (3) half-1 staged

        // ---- GEMM1 k-half 1: ks = 4..7 ----
        LOADA(aA, 6); KSTEP(aB, 4);
        LOADA(aB, 7); KSTEP(aC, 5);
        KSTEP(aA, 6);
        KSTEP(aB, 7);

        __syncthreads();   // (4) W1s dead; sH region becomes writable

        // ---- bias + LayerNorm + GELU; D layout: row = quad*4+reg, col = nt*16+n0 ----
        #pragma unroll
        for (int mt = 0; mt < 2; ++mt) {
            #pragma unroll
            for (int reg = 0; reg < 4; ++reg) {
                float s = 0.f, s2 = 0.f;
                float xv[8];
                #pragma unroll
                for (int nt = 0; nt < 8; ++nt) {
                    float x = acc[mt][nt][reg] + b1v[nt];
                    xv[nt] = x; s += x; s2 = fmaf(x, x, s2);
                }
                s  = red16(s);
                s2 = red16(s2);
                float mu  = s  * (1.0f / HDIM);
                float var = s2 * (1.0f / HDIM) - mu * mu;
                float rs  = __builtin_amdgcn_rsqf(var + 1e-5f);
                int m = w * 32 + mt * 16 + quad * 4 + reg;
                #pragma unroll
                for (int nt = 0; nt < 8; ++nt) {
                    float x = (xv[nt] - mu) * rs * lgv[nt] + lbv[nt];
                    x = gelu_exact(x);
                    sH[m * 136 + nt * 16 + n0] = f2bf(x);
                }
            }
        }
        __syncthreads();   // (5)

        // ---- GEMM2: h[128x128] x W2T[g][n=64][k=128], A from sH, B from global ----
        const unsigned short* W2Tg = W2T + (size_t)g * 64 * 128;
        f32x4 acc2[2][4];
        #pragma unroll
        for (int mt = 0; mt < 2; ++mt)
            #pragma unroll
            for (int nt2 = 0; nt2 < 4; ++nt2) acc2[mt][nt2] = (f32x4){0.f, 0.f, 0.f, 0.f};

        #pragma unroll
        for (int ks2 = 0; ks2 < 4; ++ks2) {
            s16x8 a2[2];
            #pragma unroll
            for (int mt = 0; mt < 2; ++mt)
                a2[mt] = *(const s16x8*)(&sH[(w * 32 + mt * 16 + n0) * 136 + ks2 * 32 + quad * 8]);
            #pragma unroll
            for (int nt2 = 0; nt2 < 4; ++nt2) {
                s16x8 b2f = *(const s16x8*)(W2Tg + (size_t)(nt2 * 16 + n0) * 128 + ks2 * 32 + quad * 8);
                #pragma unroll
                for (int mt = 0; mt < 2; ++mt)
                    acc2[mt][nt2] = __builtin_amdgcn_mfma_f32_16x16x32_bf16(a2[mt], b2f, acc2[mt][nt2], 0, 0, 0);
            }
        }

        // ---- epilogue: GELU + dot W3 + DPP reduce + write ----
        {
            int lo = (g == 0) ? 0   : (g == 1) ? gs1 : gs2;
            int hi = (g == 0) ? gs1 : (g == 1) ? gs2 : E;
            #pragma unroll
            for (int mt = 0; mt < 2; ++mt) {
                #pragma unroll
                for (int reg = 0; reg < 4; ++reg) {
                    float sacc = 0.f;
                    #pragma unroll
                    for (int nt2 = 0; nt2 < 4; ++nt2)
                        sacc = fmaf(gelu_exact(acc2[mt][nt2][reg] + b2v[nt2]), w3v[nt2], sacc);
                    sacc = red16(sacc);
                    if (n0 == 0) {
                        int p = pos0 + w * 32 + mt * 16 + quad * 4 + reg;
                        if (p >= lo && p < hi) out[p] = sacc + bias3;
                    }
                }
            }
        }
        __syncthreads();   // (6) sH dead before next group's staging
    }
#undef LOADA
#undef KSTEP
}

extern "C" void kernel_launch(void* const* d_in, const int* in_sizes, int n_in,
                              void* d_out, int out_size, void* d_ws, size_t ws_size,
                              hipStream_t stream) {
    const float* emb    = (const float*)d_in[0];
    const int*   edges  = (const int*)  d_in[1];
    const int*   groups = (const int*)  d_in[2];
    const float* W1     = (const float*)d_in[3];
    const float* b1     = (const float*)d_in[4];
    const float* lng    = (const float*)d_in[5];
    const float* lnb    = (const float*)d_in[6];
    const float* W2     = (const float*)d_in[7];
    const float* b2     = (const float*)d_in[8];
    const float* W3     = (const float*)d_in[9];
    const float* b3     = (const float*)d_in[10];
    float* out = (float*)d_out;
    int E        = in_sizes[2];
    int embElems = in_sizes[0];

    int nChunks = (E + 1023) / 1024;
    int embBlocks = (embElems / 8 + 255) / 256;

    // workspace layout
    unsigned short* embB = (unsigned short*)d_ws;
    unsigned short* W1S  = embB + (((size_t)embElems + 7) & ~(size_t)7);
    unsigned short* W2T  = W1S + (size_t)3 * 128 * 256;
    int* counts = (int*)(W2T + (size_t)3 * 64 * 128);
    int* bbase  = counts + (size_t)nChunks * 3;
    int* gstart = bbase  + (size_t)nChunks * 3;
    int* sorted = gstart + 4;

    k_hist   <<<dim3(nChunks),        dim3(256), 0, stream>>>(groups, E, counts);
    k_scan   <<<dim3(1),              dim3(192), 0, stream>>>(counts, nChunks, bbase, gstart, E);
    k_scatter<<<dim3(nChunks),        dim3(64),  0, stream>>>(groups, E, bbase, gstart, sorted);
    k_prep   <<<dim3(embBlocks + 60), dim3(256), 0, stream>>>(emb, embElems, embBlocks, W1, W2, embB, W1S, W2T);

    int nTiles = (E + TM - 1) / TM;
    k_mlp<<<dim3(nTiles), dim3(256), 0, stream>>>(
        embB, edges, sorted, gstart, W1S, b1, lng, lnb, W2T, b2, W3, b3, out, E);
}

// Round 2
// 245.152 us; speedup vs baseline: 1.1388x; 1.1388x over previous
//
#include <hip/hip_runtime.h>
#include <math.h>
#include <stdint.h>

#define HDIM 128
#define TM 128  // edges per block in the fused MLP kernel (32 per wave)

typedef short s16x8 __attribute__((ext_vector_type(8)));      // 8 bf16 (4 VGPRs) MFMA A/B frag
typedef float f32x4 __attribute__((ext_vector_type(4)));      // MFMA C/D frag
typedef unsigned short ushort8 __attribute__((ext_vector_type(8)));

// fp32 -> bf16 round-to-nearest-even
__device__ __forceinline__ unsigned short f2bf(float x) {
    unsigned u = __float_as_uint(x);
    u += 0x7FFFu + ((u >> 16) & 1u);
    return (unsigned short)(u >> 16);
}

// Abramowitz-Stegun 7.1.26: |err| <= 1.5e-7 absolute.
__device__ __forceinline__ float erf_fast(float x) {
    float ax = fabsf(x);
    float t = __builtin_amdgcn_rcpf(fmaf(0.3275911f, ax, 1.0f));
    float p =        fmaf(t, 1.061405429f, -1.453152027f);
    p = fmaf(t, p, 1.421413741f);
    p = fmaf(t, p, -0.284496736f);
    p = fmaf(t, p, 0.254829592f);
    float e = __builtin_amdgcn_exp2f(ax * ax * -1.4426950408889634f);
    float r = 1.0f - p * t * e;
    return copysignf(r, x);
}

__device__ __forceinline__ float gelu_exact(float x) {
    return 0.5f * x * (1.0f + erf_fast(x * 0.70710678118654752440f));
}

// full-sum over the 16 lanes of a DPP row (n0 group); all lanes get the total.
__device__ __forceinline__ float red16(float x) {
    x += __int_as_float(__builtin_amdgcn_update_dpp(0, __float_as_int(x), 0xB1,  0xF, 0xF, true)); // quad_perm [1,0,3,2]
    x += __int_as_float(__builtin_amdgcn_update_dpp(0, __float_as_int(x), 0x4E,  0xF, 0xF, true)); // quad_perm [2,3,0,1]
    x += __int_as_float(__builtin_amdgcn_update_dpp(0, __float_as_int(x), 0x141, 0xF, 0xF, true)); // row_half_mirror
    x += __int_as_float(__builtin_amdgcn_update_dpp(0, __float_as_int(x), 0x140, 0xF, 0xF, true)); // row_mirror
    return x;
}

// async global->LDS 16B per lane; LDS layout must be linear (wave-uniform base + lane*16)
__device__ __forceinline__ void async_cp16(void* lds_dst, const void* g_src) {
    __builtin_amdgcn_global_load_lds(
        (const __attribute__((address_space(1))) unsigned int*)g_src,
        (__attribute__((address_space(3))) unsigned int*)lds_dst,
        16, 0, 0);
}

// ---------------- stable counting-sort kernels ----------------

__global__ void k_hist(const int* __restrict__ groups, int E, int* __restrict__ counts) {
    __shared__ int c[3];
    int t = threadIdx.x;
    if (t < 3) c[t] = 0;
    __syncthreads();
    int base = blockIdx.x * 1024;
    for (int i = t; i < 1024; i += 256) {
        int e = base + i;
        if (e < E) atomicAdd(&c[groups[e]], 1);
    }
    __syncthreads();
    if (t < 3) counts[blockIdx.x * 3 + t] = c[t];
}

__global__ void k_scan(const int* __restrict__ counts, int nChunks,
                       int* __restrict__ bbase, int* __restrict__ gstart, int E) {
    __shared__ int tot[3];
    int t = threadIdx.x;         // block = 192
    int lane = t & 63;
    int g = t >> 6;              // 0..2
    int carry = 0;
    for (int base = 0; base < nChunks; base += 64) {
        int b = base + lane;
        int v = (b < nChunks) ? counts[b * 3 + g] : 0;
        int sc = v;
        #pragma unroll
        for (int off = 1; off < 64; off <<= 1) {
            int u = __shfl_up(sc, off);
            if (lane >= off) sc += u;
        }
        if (b < nChunks) bbase[b * 3 + g] = carry + sc - v;
        carry += __shfl(sc, 63);
    }
    if (lane == 0) tot[g] = carry;
    __syncthreads();
    if (t == 0) {
        gstart[0] = 0;
        gstart[1] = tot[0];
        gstart[2] = tot[0] + tot[1];
        gstart[3] = E;
    }
}

__global__ void k_scatter(const int* __restrict__ groups, int E,
                          const int* __restrict__ bbase, const int* __restrict__ gstart,
                          int* __restrict__ sorted) {
    int b = blockIdx.x;
    int lane = threadIdx.x;  // block = 64 (one wave)
    int run0 = gstart[0] + bbase[b * 3 + 0];
    int run1 = gstart[1] + bbase[b * 3 + 1];
    int run2 = gstart[2] + bbase[b * 3 + 2];
    unsigned long long lt = (1ull << lane) - 1ull;
    for (int p = 0; p < 16; ++p) {
        int e = b * 1024 + p * 64 + lane;
        int g = (e < E) ? groups[e] : 3;
        unsigned long long m0 = __ballot(g == 0);
        unsigned long long m1 = __ballot(g == 1);
        unsigned long long m2 = __ballot(g == 2);
        int pos = 0;
        if (g == 0) pos = run0 + __popcll(m0 & lt);
        else if (g == 1) pos = run1 + __popcll(m1 & lt);
        else if (g == 2) pos = run2 + __popcll(m2 & lt);
        if (e < E) sorted[pos] = e;
        run0 += __popcll(m0);
        run1 += __popcll(m1);
        run2 += __popcll(m2);
    }
}

// ---------------- prep: emb fp32->bf16; W1 swizzled+transposed; W2 transposed ----------------
// W1S[g][n][gk' * 8 .. +7] where gk' = gk ^ (n & 7), gk = k/8  (bank-swizzle for LDS reads;
// swizzle is closed within each 8-granule quarter, so 16KB k-quarters stage independently)
// W2T[g][n=64][k=128]
__global__ void k_prep(const float* __restrict__ emb, int embElems, int embBlocks,
                       const float* __restrict__ W1, const float* __restrict__ W2,
                       unsigned short* __restrict__ embB,
                       unsigned short* __restrict__ W1S, unsigned short* __restrict__ W2T) {
    if ((int)blockIdx.x < embBlocks) {
        int i = (blockIdx.x * 256 + threadIdx.x) * 8;
        if (i + 8 <= embElems) {
            float4 a = *(const float4*)(emb + i);
            float4 b = *(const float4*)(emb + i + 4);
            ushort8 o;
            o[0] = f2bf(a.x); o[1] = f2bf(a.y); o[2] = f2bf(a.z); o[3] = f2bf(a.w);
            o[4] = f2bf(b.x); o[5] = f2bf(b.y); o[6] = f2bf(b.z); o[7] = f2bf(b.w);
            *(ushort8*)(embB + i) = o;
        } else {
            for (int j = i; j < embElems; ++j) embB[j] = f2bf(emb[j]);
        }
        return;
    }
    int idx = (blockIdx.x - embBlocks) * 256 + threadIdx.x;
    if (idx < 3 * 32 * 128) {                    // W1S: task = (g, gk, n)
        int g  = idx >> 12;
        int r  = idx & 4095;
        int gk = r >> 7;                         // k-granule 0..31 (k0 = gk*8)
        int n  = r & 127;
        const float* src = W1 + (size_t)g * 256 * 128 + (size_t)(gk * 8) * 128 + n;
        ushort8 o;
        #pragma unroll
        for (int j = 0; j < 8; ++j) o[j] = f2bf(src[j * 128]);
        int gks = gk ^ (n & 7);                  // bank swizzle (stays within 8-granule quarter)
        *(ushort8*)(W1S + ((size_t)(g * 128 + n)) * 256 + gks * 8) = o;
    } else if (idx < 3 * 32 * 128 + 3 * 16 * 64) {
        int r2 = idx - 3 * 32 * 128;             // W2T[g][n=64][k=128]
        int g  = r2 >> 10;
        int r  = r2 & 1023;
        int kc = r >> 6;
        int n  = r & 63;
        const float* src = W2 + (size_t)g * 128 * 64 + (size_t)(kc * 8) * 64 + n;
        ushort8 o;
        #pragma unroll
        for (int j = 0; j < 8; ++j) o[j] = f2bf(src[j * 64]);
        *(ushort8*)(W2T + ((size_t)(g * 64 + n)) * 128 + kc * 8) = o;
    }
}

// ---------------- fused per-edge MLP (MFMA bf16, quarter-pipelined W1 staging) ----------------
// Block: 256 thr = 4 waves; TM=128 edges, M=32 per wave (2 m-tiles).
// LDS = 34816 B: two 16KB W1 k-quarter buffers (ping-pong); sH [128][136] overlays after GEMM1.
// Every staging issue overlaps the previous quarter's 32 MFMAs (2-phase pipeline, one
// vmcnt-drain barrier per phase). A-frags: 4 rotating pairs, loaded one phase ahead.
// Epilogue constants loaded LATE (last GEMM1 phase / pre-GEMM2) to cut peak VGPR pressure
// (round-1 spilled at the 168-reg unified cap: WRITE_SIZE 1.9MB -> 174MB).
__global__ __launch_bounds__(256, 3)
void k_mlp(const unsigned short* __restrict__ embB,
           const int* __restrict__ edges,
           const int* __restrict__ sorted,
           const int* __restrict__ gstart,
           const unsigned short* __restrict__ W1S,
           const float* __restrict__ b1,
           const float* __restrict__ lng, const float* __restrict__ lnb,
           const unsigned short* __restrict__ W2T,
           const float* __restrict__ b2,
           const float* __restrict__ W3, const float* __restrict__ b3,
           float* __restrict__ out, int E)
{
    __shared__ unsigned char smem[34816];          // W1 quarters [0,32768); sH [0,34816) overlays
    unsigned char* bufA = smem;                    // 16KB: [128 n][64 k-quarter shorts]
    unsigned char* bufB = smem + 16384;            // 16KB
    unsigned short* sH  = (unsigned short*)smem;   // [128][136] bf16

    const int t    = threadIdx.x;
    const int w    = t >> 6;        // wave 0..3
    const int lane = t & 63;
    const int n0   = lane & 15;     // MFMA 16-index
    const int quad = lane >> 4;     // MFMA k-quad / D row-group

    const int pos0 = blockIdx.x * TM;

    int gs1 = gstart[1], gs2 = gstart[2];
    int plast = (pos0 + TM - 1 < E) ? pos0 + TM - 1 : E - 1;
    int g0 = (pos0  >= gs2) ? 2 : (pos0  >= gs1) ? 1 : 0;
    int g1 = (plast >= gs2) ? 2 : (plast >= gs1) ? 1 : 0;

    // ---- per-lane A row pointers (held across the g-loop) ----
    const unsigned short* urow[2];
    const unsigned short* vrow[2];
    #pragma unroll
    for (int mt = 0; mt < 2; ++mt) {
        int p = pos0 + w * 32 + mt * 16 + n0;
        int pc = p < E ? p : E - 1;
        int e  = sorted[pc];
        urow[mt] = embB + (size_t)edges[2 * e]     * HDIM + quad * 8;
        vrow[mt] = embB + (size_t)edges[2 * e + 1] * HDIM + quad * 8;
    }

// stage 16KB k-quarter q of W1S[g] into buf (4 x cp16 per thread, linear LDS layout)
#define STAGEQ(buf, q) do {                                                              \
        _Pragma("unroll")                                                                \
        for (int r = 0; r < 4; ++r)                                                      \
            async_cp16((buf) + r * 4096 + t * 16,                                        \
                       srcg + (size_t)(r * 32 + (t >> 3)) * 512 + (q) * 128 + (t & 7) * 16); \
    } while (0)

// load A-frag pair for k-slice ks (0..3 = u-halves, 4..7 = v-halves)
#define LOADA(dst, ks) do {                                                          \
        dst[0] = *(const s16x8*)(((ks) < 4 ? urow[0] : vrow[0]) + (((ks) & 3) * 32));\
        dst[1] = *(const s16x8*)(((ks) < 4 ? urow[1] : vrow[1]) + (((ks) & 3) * 32));\
    } while (0)

// one k-slice of GEMM1 against quarter buffer bufW (8 nt, 2 mt = 16 MFMA)
#define KSTEP(areg, ks, bufW) do {                                                            \
        _Pragma("unroll")                                                                     \
        for (int nt = 0; nt < 8; ++nt) {                                                      \
            int gq = ((((ks) * 4 + quad) ^ (n0 & 7)) & 7);                                    \
            s16x8 bfrag = *(const s16x8*)(&((const unsigned short*)(bufW))[(nt * 16 + n0) * 64 + gq * 8]); \
            acc[0][nt] = __builtin_amdgcn_mfma_f32_16x16x32_bf16(areg[0], bfrag, acc[0][nt], 0, 0, 0); \
            acc[1][nt] = __builtin_amdgcn_mfma_f32_16x16x32_bf16(areg[1], bfrag, acc[1][nt], 0, 0, 0); \
        }                                                                                     \
    } while (0)

    for (int g = g0; g <= g1; ++g) {
        const unsigned char* srcg = (const unsigned char*)(W1S + (size_t)g * 128 * 256);

        f32x4 acc[2][8];
        #pragma unroll
        for (int mt = 0; mt < 2; ++mt)
            #pragma unroll
            for (int nt = 0; nt < 8; ++nt) acc[mt][nt] = (f32x4){0.f, 0.f, 0.f, 0.f};

        s16x8 aA[2], aB[2], aC[2], aD[2];

        // ---- prologue: stage q0, prefetch first two A-slices ----
        STAGEQ(bufA, 0);
        LOADA(aA, 0); LOADA(aB, 1);

        __syncthreads();   // (1) q0 staged; aA/aB arrived

        // ---- ph1: consume q0, stage q1, prefetch ks2/ks3 ----
        STAGEQ(bufB, 1);
        LOADA(aC, 2); LOADA(aD, 3);
        KSTEP(aA, 0, bufA);
        KSTEP(aB, 1, bufA);

        __syncthreads();   // (2) q1 staged; bufA reads done

        // ---- ph2: consume q1, stage q2, prefetch ks4/ks5 ----
        STAGEQ(bufA, 2);
        LOADA(aA, 4); LOADA(aB, 5);
        KSTEP(aC, 2, bufB);
        KSTEP(aD, 3, bufB);

        __syncthreads();   // (3) q2 staged; bufB reads done

        // ---- ph3: consume q2, stage q3, prefetch ks6/ks7 ----
        STAGEQ(bufB, 3);
        LOADA(aC, 6); LOADA(aD, 7);
        KSTEP(aA, 4, bufA);
        KSTEP(aB, 5, bufA);

        __syncthreads();   // (4) q3 staged; bufA reads done

        // ---- ph4: consume q3; load LN constants (used after barrier 5) ----
        float b1v[8], lgv[8], lbv[8];
        #pragma unroll
        for (int nt = 0; nt < 8; ++nt) {
            int c = nt * 16 + n0;
            b1v[nt] = b1[g * HDIM + c];
            lgv[nt] = lng[g * HDIM + c];
            lbv[nt] = lnb[g * HDIM + c];
        }
        KSTEP(aC, 6, bufB);
        KSTEP(aD, 7, bufB);

        __syncthreads();   // (5) W1 quarters dead; sH region writable

        // ---- bias + LayerNorm + GELU; D layout: row = quad*4+reg, col = nt*16+n0 ----
        #pragma unroll
        for (int mt = 0; mt < 2; ++mt) {
            #pragma unroll
            for (int reg = 0; reg < 4; ++reg) {
                float s = 0.f, s2 = 0.f;
                float xv[8];
                #pragma unroll
                for (int nt = 0; nt < 8; ++nt) {
                    float x = acc[mt][nt][reg] + b1v[nt];
                    xv[nt] = x; s += x; s2 = fmaf(x, x, s2);
                }
                s  = red16(s);
                s2 = red16(s2);
                float mu  = s  * (1.0f / HDIM);
                float var = s2 * (1.0f / HDIM) - mu * mu;
                float rs  = __builtin_amdgcn_rsqf(var + 1e-5f);
                int m = w * 32 + mt * 16 + quad * 4 + reg;
                #pragma unroll
                for (int nt = 0; nt < 8; ++nt) {
                    float x = (xv[nt] - mu) * rs * lgv[nt] + lbv[nt];
                    x = gelu_exact(x);
                    sH[m * 136 + nt * 16 + n0] = f2bf(x);
                }
            }
        }
        __syncthreads();   // (6) sH ready

        // ---- GEMM2: h[128x128] x W2T[g][n=64][k=128], A from sH, B from global ----
        const unsigned short* W2Tg = W2T + (size_t)g * 64 * 128;
        float b2v[4], w3v[4];
        #pragma unroll
        for (int nt2 = 0; nt2 < 4; ++nt2) {
            int c = nt2 * 16 + n0;
            b2v[nt2] = b2[g * 64 + c];
            w3v[nt2] = W3[g * 64 + c];
        }
        float bias3 = b3[g];

        f32x4 acc2[2][4];
        #pragma unroll
        for (int mt = 0; mt < 2; ++mt)
            #pragma unroll
            for (int nt2 = 0; nt2 < 4; ++nt2) acc2[mt][nt2] = (f32x4){0.f, 0.f, 0.f, 0.f};

        #pragma unroll
        for (int ks2 = 0; ks2 < 4; ++ks2) {
            s16x8 a2[2];
            #pragma unroll
            for (int mt = 0; mt < 2; ++mt)
                a2[mt] = *(const s16x8*)(&sH[(w * 32 + mt * 16 + n0) * 136 + ks2 * 32 + quad * 8]);
            #pragma unroll
            for (int nt2 = 0; nt2 < 4; ++nt2) {
                s16x8 b2f = *(const s16x8*)(W2Tg + (size_t)(nt2 * 16 + n0) * 128 + ks2 * 32 + quad * 8);
                #pragma unroll
                for (int mt = 0; mt < 2; ++mt)
                    acc2[mt][nt2] = __builtin_amdgcn_mfma_f32_16x16x32_bf16(a2[mt], b2f, acc2[mt][nt2], 0, 0, 0);
            }
        }

        // ---- epilogue: GELU + dot W3 + DPP reduce + write ----
        {
            int lo = (g == 0) ? 0   : (g == 1) ? gs1 : gs2;
            int hi = (g == 0) ? gs1 : (g == 1) ? gs2 : E;
            #pragma unroll
            for (int mt = 0; mt < 2; ++mt) {
                #pragma unroll
                for (int reg = 0; reg < 4; ++reg) {
                    float sacc = 0.f;
                    #pragma unroll
                    for (int nt2 = 0; nt2 < 4; ++nt2)
                        sacc = fmaf(gelu_exact(acc2[mt][nt2][reg] + b2v[nt2]), w3v[nt2], sacc);
                    sacc = red16(sacc);
                    if (n0 == 0) {
                        int p = pos0 + w * 32 + mt * 16 + quad * 4 + reg;
                        if (p >= lo && p < hi) out[p] = sacc + bias3;
                    }
                }
            }
        }
        __syncthreads();   // (7) sH dead before next group's staging
    }
#undef STAGEQ
#undef LOADA
#undef KSTEP
}

extern "C" void kernel_launch(void* const* d_in, const int* in_sizes, int n_in,
                              void* d_out, int out_size, void* d_ws, size_t ws_size,
                              hipStream_t stream) {
    const float* emb    = (const float*)d_in[0];
    const int*   edges  = (const int*)  d_in[1];
    const int*   groups = (const int*)  d_in[2];
    const float* W1     = (const float*)d_in[3];
    const float* b1     = (const float*)d_in[4];
    const float* lng    = (const float*)d_in[5];
    const float* lnb    = (const float*)d_in[6];
    const float* W2     = (const float*)d_in[7];
    const float* b2     = (const float*)d_in[8];
    const float* W3     = (const float*)d_in[9];
    const float* b3     = (const float*)d_in[10];
    float* out = (float*)d_out;
    int E        = in_sizes[2];
    int embElems = in_sizes[0];

    int nChunks = (E + 1023) / 1024;
    int embBlocks = (embElems / 8 + 255) / 256;

    // workspace layout
    unsigned short* embB = (unsigned short*)d_ws;
    unsigned short* W1S  = embB + (((size_t)embElems + 7) & ~(size_t)7);
    unsigned short* W2T  = W1S + (size_t)3 * 128 * 256;
    int* counts = (int*)(W2T + (size_t)3 * 64 * 128);
    int* bbase  = counts + (size_t)nChunks * 3;
    int* gstart = bbase  + (size_t)nChunks * 3;
    int* sorted = gstart + 4;

    k_hist   <<<dim3(nChunks),        dim3(256), 0, stream>>>(groups, E, counts);
    k_scan   <<<dim3(1),              dim3(192), 0, stream>>>(counts, nChunks, bbase, gstart, E);
    k_scatter<<<dim3(nChunks),        dim3(64),  0, stream>>>(groups, E, bbase, gstart, sorted);
    k_prep   <<<dim3(embBlocks + 60), dim3(256), 0, stream>>>(emb, embElems, embBlocks, W1, W2, embB, W1S, W2T);

    int nTiles = (E + TM - 1) / TM;
    k_mlp<<<dim3(nTiles), dim3(256), 0, stream>>>(
        embB, edges, sorted, gstart, W1S, b1, lng, lnb, W2T, b2, W3, b3, out, E);
}